// Round 15
// baseline (390.085 us; speedup 1.0000x reference)
//
#include <hip/hip_runtime.h>
#include <stdint.h>

typedef unsigned short u16;
typedef __attribute__((ext_vector_type(8))) short short8;
typedef __attribute__((ext_vector_type(4))) float f32x4;

#define M_DIM 8192
#define N_DIM 4096
#define K_DIM 4096

// ---------- fp32 -> bf16 (RNE), 8 elems/thread ----------
__device__ inline u16 f32_to_bf16_rne(float f) {
    uint32_t b = __builtin_bit_cast(uint32_t, f);
    b += 0x7fffu + ((b >> 16) & 1u);
    return (u16)(b >> 16);
}

__global__ __launch_bounds__(256)
void cvt_f32_to_bf16_k(const float* __restrict__ in, u16* __restrict__ out, int n_vec8) {
    int stride = gridDim.x * blockDim.x;
    for (int i = blockIdx.x * blockDim.x + threadIdx.x; i < n_vec8; i += stride) {
        const float4* p = reinterpret_cast<const float4*>(in) + 2 * (size_t)i;
        float4 a = p[0];
        float4 b = p[1];
        float v[8] = {a.x, a.y, a.z, a.w, b.x, b.y, b.z, b.w};
        short8 r;
#pragma unroll
        for (int j = 0; j < 8; ++j) r[j] = (short)f32_to_bf16_rne(v[j]);
        *reinterpret_cast<short8*>(out + 8 * (size_t)i) = r;
    }
}

// ---------- 128x128 bf16 GEMM: 4-deep DMA pipeline, 2 blocks/CU ----------
// A: [M][K] bf16, B: [N][K] bf16 (B^T), C: [M][N] f32
// 256 threads = 4 waves (2M x 2N); per-wave output 64x64; BK=32 (one MFMA-K).
// LDS: 4 buffers x (A 128x32 + B 128x32) bf16 = 4 x 16 KiB = 64 KiB
//   -> 2 blocks/CU: two INDEPENDENT barrier groups; one block's waits are
//      covered by the other's MFMA (TLP), on top of a stall-free schedule.
//
// Pipeline (tile t lives in buf[t&3]; body t = one K=32 step):
//   VM(4)    outstanding = t+1's 4 + t+2's 4 -> drains tile t+1 (issued at
//            body t-2, TWO bodies ago ~2.5k cyc >> 900 cyc HBM: no stall)
//   BAR      publishes tile t+1 (single barrier per body)
//   rd set[(t+1)&1] <- buf[(t+1)&3]   (8 ds_read_b128, drain under MFMA)
//   STAGE tile t+3 -> buf[(t+3)&3]    (4 DMA; buffer held tile t-1, whose
//            reads drained at body t-1 LGKM and were published by this BAR)
//   LGKM(8)  drains exactly prev body's 8 reads (this body's 8 stay in flight)
//   setprio(1); 16 MFMA (4m x 4n, set[t&1]); setprio(0)
// Reg sets alternate by parity: set written at body t is consumed at t+1,
// rewritten at t+2 (>=1 body after last use).
// Swizzle (64B rows, r14 HW-validated, 0 conflicts): chunk map
// cl = (cp&~3)|((cp&3)^((cp>>3)&3)); read key=((lane&15)>>1)&3,
// cpos=((lane>>4)<<4)^(key<<4).

#define BAR() do { asm volatile("" ::: "memory"); __builtin_amdgcn_s_barrier(); asm volatile("" ::: "memory"); } while (0)
#define LGKM(n) do { asm volatile("s_waitcnt lgkmcnt(" #n ")" ::: "memory"); __builtin_amdgcn_sched_barrier(0); } while (0)
#define WAIT_VM8() asm volatile("s_waitcnt vmcnt(8)" ::: "memory")
#define WAIT_VM4() asm volatile("s_waitcnt vmcnt(4)" ::: "memory")
#define WAIT_VM0() asm volatile("s_waitcnt vmcnt(0)" ::: "memory")
#define SB0() __builtin_amdgcn_sched_barrier(0)

#define MFMA16(AA, BB)                                                            \
    _Pragma("unroll")                                                             \
    for (int m = 0; m < 4; ++m) {                                                 \
        _Pragma("unroll")                                                         \
        for (int n = 0; n < 4; ++n) {                                             \
            acc[m][n] = __builtin_amdgcn_mfma_f32_16x16x32_bf16(                  \
                AA[m], BB[n], acc[m][n], 0, 0, 0);                                \
        }                                                                         \
    }

#define READ8(AA, BB, PA, PB)                                                     \
    _Pragma("unroll")                                                             \
    for (int m = 0; m < 4; ++m) {                                                 \
        AA[m] = *reinterpret_cast<const short8*>((PA) + m * 1024);                \
    }                                                                             \
    _Pragma("unroll")                                                             \
    for (int n = 0; n < 4; ++n) {                                                 \
        BB[n] = *reinterpret_cast<const short8*>((PB) + n * 1024);                \
    }

__global__ __launch_bounds__(256, 4)
void gemm_pipe4(const u16* __restrict__ A, const u16* __restrict__ B,
                const float* __restrict__ bias, float* __restrict__ C) {
    // buf b: A = lds[b][0..4095], B = lds[b][4096..8191]  (16 KiB each)
    __shared__ __align__(16) u16 lds[4][8192];   // 64 KiB

    const int tid  = threadIdx.x;
    const int wave = tid >> 6;      // 0..3
    const int lane = tid & 63;

    // XCD-aware bijective swizzle (nwg=2048, %8==0)
    const uint32_t wg = (blockIdx.x & 7u) * 256u + (blockIdx.x >> 3);
    const uint32_t nbx = N_DIM / 128;   // 32
    const int bx = (int)(wg % nbx);
    const int by = (int)(wg / nbx);
    const int brow = by * 128;
    const int bcol = bx * 128;

    const int wr = wave >> 1;   // 0..1 -> 64 output rows
    const int wc = wave & 1;    // 0..1 -> 64 output cols

    // DMA source maps: A/B regions each 128x32 = 512 chunks; 2 chunks/thread
    uint32_t rS[2], cS[2];
#pragma unroll
    for (int j = 0; j < 2; ++j) {
        const uint32_t cp = (uint32_t)tid + 256u * j;
        const uint32_t cl = (cp & ~3u) | ((cp & 3u) ^ ((cp >> 3) & 3u));
        rS[j] = cl >> 2;           // row 0..127
        cS[j] = (cl & 3u) * 8u;    // col in u16
    }

    const u16* gA = A + (size_t)brow * K_DIM;
    const u16* gB = B + (size_t)bcol * K_DIM;

    auto STAGE = [&](int b, int k0) {
        u16* la = &lds[b][0];
        u16* lb = &lds[b][4096];
#pragma unroll
        for (int j = 0; j < 2; ++j) {
            __builtin_amdgcn_global_load_lds(
                (const __attribute__((address_space(1))) uint32_t*)(gA + (size_t)rS[j] * K_DIM + k0 + cS[j]),
                (__attribute__((address_space(3))) uint32_t*)(la + wave * 512 + j * 2048), 16, 0, 0);
        }
#pragma unroll
        for (int j = 0; j < 2; ++j) {
            __builtin_amdgcn_global_load_lds(
                (const __attribute__((address_space(1))) uint32_t*)(gB + (size_t)rS[j] * K_DIM + k0 + cS[j]),
                (__attribute__((address_space(3))) uint32_t*)(lb + wave * 512 + j * 2048), 16, 0, 0);
        }
    };

    // per-lane swizzled read bases for each buffer
    const uint32_t key  = (((uint32_t)lane & 15u) >> 1) & 3u;
    const uint32_t cpos = (((uint32_t)lane >> 4) << 4) ^ (key << 4);
    const uint32_t arow = ((uint32_t)wr * 64u + ((uint32_t)lane & 15u)) * 64u;
    const uint32_t brw  = ((uint32_t)wc * 64u + ((uint32_t)lane & 15u)) * 64u;

    const char* pA[4];
    const char* pB[4];
#pragma unroll
    for (int b = 0; b < 4; ++b) {
        pA[b] = (const char*)&lds[b][0]    + arow + cpos;
        pB[b] = (const char*)&lds[b][4096] + brw  + cpos;
    }

    f32x4 acc[4][4];
#pragma unroll
    for (int m = 0; m < 4; ++m)
#pragma unroll
        for (int n = 0; n < 4; ++n) acc[m][n] = (f32x4){0.f, 0.f, 0.f, 0.f};

    short8 a0[4], b0[4], a1[4], b1[4];   // parity sets

    // ---- prologue: stage tiles 0,1,2 (12 DMA); VM(8) drains tile 0; read set0 ----
    STAGE(0, 0);
    STAGE(1, 32);
    STAGE(2, 64);
    WAIT_VM8();
    BAR();
    READ8(a0, b0, pA[0], pB[0]);

    // ---- main loop: 32 iters x 4 bodies (t = 4i+j; buf = j, parity = j&1) ----
    for (int i = 0; i < K_DIM / 128; ++i) {
        const int t0 = 4 * i;

        // body j=0: t=t0, MFMA set0, read set1 <- buf1, stage t+3 -> buf3
        WAIT_VM4();
        BAR();
        READ8(a1, b1, pA[1], pB[1]);
        STAGE(3, ((t0 + 3) * 32) & (K_DIM - 1));
        LGKM(8);
        __builtin_amdgcn_s_setprio(1);
        MFMA16(a0, b0);
        __builtin_amdgcn_s_setprio(0);

        // body j=1: t=t0+1, MFMA set1, read set0 <- buf2, stage t+3 -> buf0
        WAIT_VM4();
        BAR();
        READ8(a0, b0, pA[2], pB[2]);
        STAGE(0, ((t0 + 4) * 32) & (K_DIM - 1));
        LGKM(8);
        __builtin_amdgcn_s_setprio(1);
        MFMA16(a1, b1);
        __builtin_amdgcn_s_setprio(0);

        // body j=2: t=t0+2, MFMA set0, read set1 <- buf3, stage t+3 -> buf1
        WAIT_VM4();
        BAR();
        READ8(a1, b1, pA[3], pB[3]);
        STAGE(1, ((t0 + 5) * 32) & (K_DIM - 1));
        LGKM(8);
        __builtin_amdgcn_s_setprio(1);
        MFMA16(a0, b0);
        __builtin_amdgcn_s_setprio(0);

        // body j=3: t=t0+3, MFMA set1, read set0 <- buf0, stage t+3 -> buf2
        WAIT_VM4();
        BAR();
        READ8(a0, b0, pA[0], pB[0]);
        STAGE(2, ((t0 + 6) * 32) & (K_DIM - 1));
        LGKM(8);
        __builtin_amdgcn_s_setprio(1);
        MFMA16(a1, b1);
        __builtin_amdgcn_s_setprio(0);
    }

    WAIT_VM0();   // drain wrapped prefetches
    LGKM(0);      // drain dangling reads before epilogue reuses regs

    // ---- epilogue: C/D layout col=lane&15, row=(lane>>4)*4+j ----
    const int orow = brow + wr * 64 + (lane >> 4) * 4;
    const int ocol = bcol + wc * 64 + (lane & 15);
#pragma unroll
    for (int n = 0; n < 4; ++n) {
        const int c = ocol + n * 16;
        const float bv = bias[c];
#pragma unroll
        for (int m = 0; m < 4; ++m) {
#pragma unroll
            for (int j = 0; j < 4; ++j) {
                C[(size_t)(orow + m * 16 + j) * N_DIM + c] = acc[m][n][j] + bv;
            }
        }
    }
}

// ---------- fallback (ws too small): correct, slow fp32 ----------
__global__ __launch_bounds__(256)
void gemm_f32_naive(const float* __restrict__ x, const float* __restrict__ w,
                    const float* __restrict__ bias, float* __restrict__ out) {
    const size_t total = (size_t)M_DIM * N_DIM;
    const size_t stride = (size_t)gridDim.x * blockDim.x;
    for (size_t idx = (size_t)blockIdx.x * blockDim.x + threadIdx.x; idx < total; idx += stride) {
        const int b = (int)(idx / N_DIM);
        const int o = (int)(idx % N_DIM);
        const float* xr = x + (size_t)b * K_DIM;
        const float* wr = w + (size_t)o * K_DIM;
        float s = bias[o];
        for (int k = 0; k < K_DIM; ++k) s = fmaf(xr[k], wr[k], s);
        out[idx] = s;
    }
}

extern "C" void kernel_launch(void* const* d_in, const int* in_sizes, int n_in,
                              void* d_out, int out_size, void* d_ws, size_t ws_size,
                              hipStream_t stream) {
    const float* x    = (const float*)d_in[0];
    const float* w    = (const float*)d_in[1];
    const float* bias = (const float*)d_in[2];
    float* out = (float*)d_out;

    const size_t xb_elems = (size_t)M_DIM * K_DIM;
    const size_t wb_elems = (size_t)N_DIM * K_DIM;
    const size_t need = (xb_elems + wb_elems) * sizeof(u16);

    if (ws_size >= need) {
        u16* xb = (u16*)d_ws;
        u16* wb = xb + xb_elems;
        cvt_f32_to_bf16_k<<<2048, 256, 0, stream>>>(x, xb, (int)(xb_elems / 8));
        cvt_f32_to_bf16_k<<<2048, 256, 0, stream>>>(w, wb, (int)(wb_elems / 8));
        const int nwg = (M_DIM / 128) * (N_DIM / 128);   // 64*32 = 2048
        gemm_pipe4<<<nwg, 256, 0, stream>>>(xb, wb, bias, out);
    } else {
        gemm_f32_naive<<<4096, 256, 0, stream>>>(x, w, bias, out);
    }
}

// Round 16
// 272.949 us; speedup vs baseline: 1.4291x; 1.4291x over previous
//
#include <hip/hip_runtime.h>
#include <stdint.h>

typedef unsigned short u16;
typedef __attribute__((ext_vector_type(8))) short short8;
typedef __attribute__((ext_vector_type(4))) float f32x4;

#define M_DIM 8192
#define N_DIM 4096
#define K_DIM 4096

// ---------- fused fp32 -> bf16 (RNE) for x and w in one launch ----------
__device__ inline u16 f32_to_bf16_rne(float f) {
    uint32_t b = __builtin_bit_cast(uint32_t, f);
    b += 0x7fffu + ((b >> 16) & 1u);
    return (u16)(b >> 16);
}

__global__ __launch_bounds__(256)
void cvt_both_k(const float* __restrict__ x, u16* __restrict__ xb, int nx_vec8,
                const float* __restrict__ w, u16* __restrict__ wb, int nw_vec8) {
    const int total = nx_vec8 + nw_vec8;
    const int stride = gridDim.x * blockDim.x;
    for (int i = blockIdx.x * blockDim.x + threadIdx.x; i < total; i += stride) {
        const float* in;
        u16* out;
        int idx;
        if (i < nx_vec8) { in = x; out = xb; idx = i; }
        else             { in = w; out = wb; idx = i - nx_vec8; }
        const float4* p = reinterpret_cast<const float4*>(in) + 2 * (size_t)idx;
        float4 a = p[0];
        float4 b = p[1];
        float v[8] = {a.x, a.y, a.z, a.w, b.x, b.y, b.z, b.w};
        short8 r;
#pragma unroll
        for (int j = 0; j < 8; ++j) r[j] = (short)f32_to_bf16_rne(v[j]);
        *reinterpret_cast<short8*>(out + 8 * (size_t)idx) = r;
    }
}

// ---------- 256x256 8-phase bf16 GEMM: counted-lgkm JIT pipeline (r10 best) ----------
// A: [M][K] bf16, B: [N][K] bf16 (B^T), C: [M][N] f32
// 512 threads = 8 waves (2M x 4N); per-wave 128x64; BK=64.
// LDS: [dbuf][mat][half][128*64] bf16 = 128 KiB. Swizzle S(a)=a^(((a>>7)&7)<<4)
// folded into precomputed per-lane base pointers (8: buf x mat x ks).
//
// Quad16 = 4m x 4n MFMA at ONE k-slice. Tile order: (mh0,k0)(mh0,k1)(mh1,k0)
// (mh1,k1). Reads JIT ONE PHASE AHEAD; post-barrier wait is the COUNTED
// lgkmcnt(N = reads issued this phase): drains exactly the prior phase's
// reads while this phase's drain under the MFMA cluster. Reads/phase:
// 8,4,4,8,8,4,4,8.
//   P1: rd aB<-a.mh0k1, bB<-a.k1 | st b.Ah0      | lgkm(8) | Q(aA,bA,mh0)
//   P2: rd aA<-a.mh1k0           | st b.Ah1      | lgkm(4) | Q(aB,bB,mh0)
//   P3: rd aB<-a.mh1k1           | st (a+2).Bh0  | lgkm(4) | Q(aA,bA,mh1) | vm(2)
//   P4: rd aA<-b.mh0k0, bA<-b.k0 | st (a+2).Bh1  | lgkm(8) | Q(aB,bB,mh1)
//   P5: rd aB<-b.mh0k1, bB<-b.k1 | st (a+2).Ah0  | lgkm(8) | Q(aA,bA,mh0)
//   P6: rd aA<-b.mh1k0           | st (a+2).Ah1  | lgkm(4) | Q(aB,bB,mh0)
//   P7: rd aB<-b.mh1k1           | st (b+2).Bh0  | lgkm(4) | Q(aA,bA,mh1) | vm(2)
//   P8: rd aA<-a'.mh0k0,bA<-a'.k0| st (b+2).Bh1  | lgkm(8) | Q(aB,bB,mh1)
// Stage WAR: buf0.B free P2-close (stage P3/P4), buf0.A free P4-close (P5/P6),
// buf1.B free P6-close (P7/P8), buf1.A free P8-close (P1/P2).
// vm(2)@P3 drains tile b (prev-P7,P8,P1,P2); vm(2)@P7 drains a+2 (P3..P6).

#define BAR() do { asm volatile("" ::: "memory"); __builtin_amdgcn_s_barrier(); asm volatile("" ::: "memory"); } while (0)
#define LGKM(n) do { asm volatile("s_waitcnt lgkmcnt(" #n ")" ::: "memory"); __builtin_amdgcn_sched_barrier(0); } while (0)
#define WAIT_VM4() asm volatile("s_waitcnt vmcnt(4)" ::: "memory")
#define WAIT_VM2() asm volatile("s_waitcnt vmcnt(2)" ::: "memory")
#define WAIT_VM0() asm volatile("s_waitcnt vmcnt(0)" ::: "memory")

// 16 MFMA: 4 m-frags x 4 n-frags at one k-slice
#define QUAD16(AA, BB, MH)                                                        \
    _Pragma("unroll")                                                             \
    for (int m = 0; m < 4; ++m) {                                                 \
        _Pragma("unroll")                                                         \
        for (int n = 0; n < 4; ++n) {                                             \
            acc[(MH) * 4 + m][n] =                                                \
                __builtin_amdgcn_mfma_f32_16x16x32_bf16(                          \
                    AA[m], BB[n], acc[(MH) * 4 + m][n], 0, 0, 0);                 \
        }                                                                         \
    }

#define READ_A4(AA, P, MHOFF)                                                     \
    _Pragma("unroll")                                                             \
    for (int m = 0; m < 4; ++m) {                                                 \
        AA[m] = *reinterpret_cast<const short8*>((P) + (MHOFF) + m * 2048);       \
    }

#define READ_B4(BB, P)                                                            \
    _Pragma("unroll")                                                             \
    for (int n = 0; n < 4; ++n) {                                                 \
        BB[n] = *reinterpret_cast<const short8*>((P) + n * 2048);                 \
    }

__global__ __launch_bounds__(512, 2)
void gemm_8phase(const u16* __restrict__ A, const u16* __restrict__ B,
                 const float* __restrict__ bias, float* __restrict__ C) {
    __shared__ __align__(16) u16 lds[2][2][2][128 * 64];   // 128 KiB

    const int tid  = threadIdx.x;
    const int wave = tid >> 6;
    const int lane = tid & 63;

    // T1: XCD-aware bijective swizzle (nwg=512, 512%8==0)
    const uint32_t wg = (blockIdx.x & 7u) * 64u + (blockIdx.x >> 3);
    const int bx = (int)(wg % (N_DIM / 256));
    const int by = (int)(wg / (N_DIM / 256));
    const int brow = by * 256;
    const int bcol = bx * 256;

    const int wr = wave >> 2;   // 0..1 -> 128 output rows each
    const int wc = wave & 3;    // 0..3 -> 64 output cols each

    // staging: physical chunk cp (linear gload_lds dest) holds LOGICAL chunk
    // cl = cp ^ ((cp>>3)&7)  (16B-chunk form of S; involution)
    const uint32_t cp0 = (uint32_t)(wave * 64 + lane);
    const uint32_t cp1 = cp0 + 512u;
    const uint32_t cl0 = cp0 ^ ((cp0 >> 3) & 7u);
    const uint32_t cl1 = cp1 ^ ((cp1 >> 3) & 7u);
    const uint32_t sr0 = cl0 >> 3, sc0 = (cl0 & 7u) * 8u;
    const uint32_t sr1 = cl1 >> 3, sc1 = (cl1 & 7u) * 8u;

    const u16* pA[2] = { A + (size_t)(brow)       * K_DIM,
                         A + (size_t)(brow + 128) * K_DIM };
    const u16* pB[2] = { B + (size_t)(bcol)       * K_DIM,
                         B + (size_t)(bcol + 128) * K_DIM };

    // precomputed swizzled per-lane ds_read bases (ks in {0,64B} folded)
    const uint32_t kb   = (uint32_t)(lane >> 4) * 16u;
    const uint32_t sw   = (uint32_t)(lane & 7) << 4;
    const uint32_t aoff = (uint32_t)(lane & 15) * 128u + kb;
    const uint32_t boff = (uint32_t)(wc & 1) * 8192u + (uint32_t)(lane & 15) * 128u + kb;

    const char* As0 = (const char*)&lds[0][0][wr][0];
    const char* As1 = (const char*)&lds[1][0][wr][0];
    const char* Bs0 = (const char*)&lds[0][1][wc >> 1][0];
    const char* Bs1 = (const char*)&lds[1][1][wc >> 1][0];

    const char* pA0k0 = As0 + ((aoff)        ^ sw);
    const char* pA0k1 = As0 + ((aoff + 64u)  ^ sw);
    const char* pA1k0 = As1 + ((aoff)        ^ sw);
    const char* pA1k1 = As1 + ((aoff + 64u)  ^ sw);
    const char* pB0k0 = Bs0 + ((boff)        ^ sw);
    const char* pB0k1 = Bs0 + ((boff + 64u)  ^ sw);
    const char* pB1k0 = Bs1 + ((boff)        ^ sw);
    const char* pB1k1 = Bs1 + ((boff + 64u)  ^ sw);

    auto STAGE = [&](const u16* gbase, u16* lhalf, int k0) {
        __builtin_amdgcn_global_load_lds(
            (const __attribute__((address_space(1))) uint32_t*)(gbase + (size_t)sr0 * K_DIM + k0 + sc0),
            (__attribute__((address_space(3))) uint32_t*)(lhalf + wave * 512), 16, 0, 0);
        __builtin_amdgcn_global_load_lds(
            (const __attribute__((address_space(1))) uint32_t*)(gbase + (size_t)sr1 * K_DIM + k0 + sc1),
            (__attribute__((address_space(3))) uint32_t*)(lhalf + 4096 + wave * 512), 16, 0, 0);
    };

    f32x4 acc[8][4];
#pragma unroll
    for (int m = 0; m < 8; ++m)
#pragma unroll
        for (int n = 0; n < 4; ++n) acc[m][n] = (f32x4){0.f, 0.f, 0.f, 0.f};

    short8 aA[4], aB[4], bA[4], bB[4];

    // ---- prologue: tile a=0 (8 loads) + b.Bh0/Bh1 (4 loads); vmcnt(4);
    //      pre-read R(P1) = aA<-a.mh0k0, bA<-a.k0 ----
    STAGE(pA[0], &lds[0][0][0][0], 0);
    STAGE(pA[1], &lds[0][0][1][0], 0);
    STAGE(pB[0], &lds[0][1][0][0], 0);
    STAGE(pB[1], &lds[0][1][1][0], 0);
    STAGE(pB[0], &lds[1][1][0][0], 64);
    STAGE(pB[1], &lds[1][1][1][0], 64);
    WAIT_VM4();
    BAR();
    READ_A4(aA, pA0k0, 0);
    READ_B4(bA, pB0k0);

    // ---- main loop: iter i computes tiles a=2i (buf0), b=2i+1 (buf1) ----
    for (int i = 0; i < K_DIM / 128; ++i) {
        const int k_b  = (2 * i + 1) * 64;
        const int k_a2 = ((2 * i + 2) * 64) & (K_DIM - 1);
        const int k_b2 = ((2 * i + 3) * 64) & (K_DIM - 1);

        // P1: rd aB<-a.mh0k1, bB<-a.k1 (8) | st b.Ah0 | Q(aA,bA,mh0)
        READ_A4(aB, pA0k1, 0);
        READ_B4(bB, pB0k1);
        STAGE(pA[0], &lds[1][0][0][0], k_b);
        BAR(); LGKM(8);
        __builtin_amdgcn_s_setprio(1);
        QUAD16(aA, bA, 0);
        __builtin_amdgcn_s_setprio(0);
        BAR();

        // P2: rd aA<-a.mh1k0 (4) | st b.Ah1 | Q(aB,bB,mh0)
        READ_A4(aA, pA0k0, 8192);
        STAGE(pA[1], &lds[1][0][1][0], k_b);
        BAR(); LGKM(4);
        __builtin_amdgcn_s_setprio(1);
        QUAD16(aB, bB, 0);
        __builtin_amdgcn_s_setprio(0);
        BAR();

        // P3: rd aB<-a.mh1k1 (4) | st (a+2).Bh0 | Q(aA,bA,mh1) | vm(2): publish b
        READ_A4(aB, pA0k1, 8192);
        STAGE(pB[0], &lds[0][1][0][0], k_a2);
        BAR(); LGKM(4);
        __builtin_amdgcn_s_setprio(1);
        QUAD16(aA, bA, 1);
        __builtin_amdgcn_s_setprio(0);
        WAIT_VM2();
        BAR();

        // P4: rd aA<-b.mh0k0, bA<-b.k0 (8) | st (a+2).Bh1 | Q(aB,bB,mh1)
        READ_A4(aA, pA1k0, 0);
        READ_B4(bA, pB1k0);
        STAGE(pB[1], &lds[0][1][1][0], k_a2);
        BAR(); LGKM(8);
        __builtin_amdgcn_s_setprio(1);
        QUAD16(aB, bB, 1);
        __builtin_amdgcn_s_setprio(0);
        BAR();

        // P5: rd aB<-b.mh0k1, bB<-b.k1 (8) | st (a+2).Ah0 | Q(aA,bA,mh0)
        READ_A4(aB, pA1k1, 0);
        READ_B4(bB, pB1k1);
        STAGE(pA[0], &lds[0][0][0][0], k_a2);
        BAR(); LGKM(8);
        __builtin_amdgcn_s_setprio(1);
        QUAD16(aA, bA, 0);
        __builtin_amdgcn_s_setprio(0);
        BAR();

        // P6: rd aA<-b.mh1k0 (4) | st (a+2).Ah1 | Q(aB,bB,mh0)
        READ_A4(aA, pA1k0, 8192);
        STAGE(pA[1], &lds[0][0][1][0], k_a2);
        BAR(); LGKM(4);
        __builtin_amdgcn_s_setprio(1);
        QUAD16(aB, bB, 0);
        __builtin_amdgcn_s_setprio(0);
        BAR();

        // P7: rd aB<-b.mh1k1 (4) | st (b+2).Bh0 | Q(aA,bA,mh1) | vm(2): publish a+2
        READ_A4(aB, pA1k1, 8192);
        STAGE(pB[0], &lds[1][1][0][0], k_b2);
        BAR(); LGKM(4);
        __builtin_amdgcn_s_setprio(1);
        QUAD16(aA, bA, 1);
        __builtin_amdgcn_s_setprio(0);
        WAIT_VM2();
        BAR();

        // P8: rd aA<-(a+2).mh0k0, bA<-(a+2).k0 (8) | st (b+2).Bh1 | Q(aB,bB,mh1)
        READ_A4(aA, pA0k0, 0);
        READ_B4(bA, pB0k0);
        STAGE(pB[1], &lds[1][1][1][0], k_b2);
        BAR(); LGKM(8);
        __builtin_amdgcn_s_setprio(1);
        QUAD16(aB, bB, 1);
        __builtin_amdgcn_s_setprio(0);
        BAR();
    }

    WAIT_VM0();    // drain wrapped prefetches
    LGKM(0);       // drain dangling JIT reads before epilogue reuses regs

    // ---- epilogue: C/D layout col=lane&15, row=(lane>>4)*4+j ----
    const int orow = brow + wr * 128 + (lane >> 4) * 4;
    const int ocol = bcol + wc * 64 + (lane & 15);
#pragma unroll
    for (int n = 0; n < 4; ++n) {
        const int c = ocol + n * 16;
        const float bv = bias[c];
#pragma unroll
        for (int m = 0; m < 8; ++m) {
#pragma unroll
            for (int j = 0; j < 4; ++j) {
                C[(size_t)(orow + m * 16 + j) * N_DIM + c] = acc[m][n][j] + bv;
            }
        }
    }
}

// ---------- fallback (ws too small): correct, slow fp32 ----------
__global__ __launch_bounds__(256)
void gemm_f32_naive(const float* __restrict__ x, const float* __restrict__ w,
                    const float* __restrict__ bias, float* __restrict__ out) {
    const size_t total = (size_t)M_DIM * N_DIM;
    const size_t stride = (size_t)gridDim.x * blockDim.x;
    for (size_t idx = (size_t)blockIdx.x * blockDim.x + threadIdx.x; idx < total; idx += stride) {
        const int b = (int)(idx / N_DIM);
        const int o = (int)(idx % N_DIM);
        const float* xr = x + (size_t)b * K_DIM;
        const float* wr = w + (size_t)o * K_DIM;
        float s = bias[o];
        for (int k = 0; k < K_DIM; ++k) s = fmaf(xr[k], wr[k], s);
        out[idx] = s;
    }
}

extern "C" void kernel_launch(void* const* d_in, const int* in_sizes, int n_in,
                              void* d_out, int out_size, void* d_ws, size_t ws_size,
                              hipStream_t stream) {
    const float* x    = (const float*)d_in[0];
    const float* w    = (const float*)d_in[1];
    const float* bias = (const float*)d_in[2];
    float* out = (float*)d_out;

    const size_t xb_elems = (size_t)M_DIM * K_DIM;
    const size_t wb_elems = (size_t)N_DIM * K_DIM;
    const size_t need = (xb_elems + wb_elems) * sizeof(u16);

    if (ws_size >= need) {
        u16* xb = (u16*)d_ws;
        u16* wb = xb + xb_elems;
        cvt_both_k<<<2048, 256, 0, stream>>>(x, xb, (int)(xb_elems / 8),
                                             w, wb, (int)(wb_elems / 8));
        const int nwg = (M_DIM / 256) * (N_DIM / 256);   // 32*16 = 512
        gemm_8phase<<<nwg, 512, 0, stream>>>(xb, wb, bias, out);
    } else {
        gemm_f32_naive<<<4096, 256, 0, stream>>>(x, w, bias, out);
    }
}